// Round 1
// baseline (115.486 us; speedup 1.0000x reference)
//
#include <hip/hip_runtime.h>
#include <hip/hip_bf16.h>

// Problem constants
#define BB 4
#define NN 2048
#define DD 256
#define HH 8
#define ZZ 64
#define SPLIT 8
#define CHUNK (NN/SPLIT)   // 256
#define NTILES (NN/16)     // 128

typedef __attribute__((ext_vector_type(8))) short bf16x8;
typedef __attribute__((ext_vector_type(4))) float f32x4;
typedef __attribute__((ext_vector_type(4))) unsigned short us4;
typedef __attribute__((ext_vector_type(8))) unsigned short us8;

static __device__ __forceinline__ unsigned short f2bf(float f){
  unsigned int u = __float_as_uint(f);
  u = (u + 0x7fffu + ((u>>16)&1u)) >> 16;   // RNE truncate to bf16
  return (unsigned short)u;
}

// ---------------------------------------------------------------------------
// Kernel 0: convert g (f32 -> bf16) and Wq||Wk (f32 -> bf16, [1024][256]),
// and zero the output scalar (d_out is poisoned before timing).
// g: 2,097,152 floats -> 524288 float4; W: 2*131072 floats -> 65536 float4.
// ---------------------------------------------------------------------------
__global__ __launch_bounds__(256) void cvt_kernel(
    const float* __restrict__ g, const float* __restrict__ Wq,
    const float* __restrict__ Wk, unsigned short* __restrict__ gb,
    unsigned short* __restrict__ wb, float* __restrict__ out)
{
  int idx = blockIdx.x*256 + threadIdx.x;
  if (idx == 0) out[0] = 0.0f;
  if (idx < 524288){
    const float4 v = ((const float4*)g)[idx];
    us4 o = { f2bf(v.x), f2bf(v.y), f2bf(v.z), f2bf(v.w) };
    *(us4*)(gb + (size_t)idx*4) = o;
  } else {
    int j = idx - 524288;                   // 0..65535
    const float4 v = (j < 32768) ? ((const float4*)Wq)[j]
                                 : ((const float4*)Wk)[j - 32768];
    us4 o = { f2bf(v.x), f2bf(v.y), f2bf(v.z), f2bf(v.w) };
    int dst = (j < 32768) ? j*4 : 131072 + (j - 32768)*4;
    *(us4*)(wb + dst) = o;
  }
}

// ---------------------------------------------------------------------------
// Kernel 1: projection GEMM. out[row, c] = sum_d gb[row,d] * wb[c,d]
// row = b*2048+n (8192 rows), c = (is_k*8 + h)*64 + z (1024 cols), K = 256.
// Block: 256 thr (4 waves), 64x64 tile, K-steps of 32 staged in LDS (padded
// +8 bf16 -> row stride 80B keeps ds_read_b128 16B-aligned, ~2-way banks).
// Output layout: q/k [b][h][n][z] bf16 so attention frags are 16B/lane loads.
// ---------------------------------------------------------------------------
__global__ __launch_bounds__(256) void proj_kernel(
    const unsigned short* __restrict__ gb, const unsigned short* __restrict__ wb,
    unsigned short* __restrict__ qb, unsigned short* __restrict__ kb)
{
  __shared__ __align__(16) unsigned short As[64][40];
  __shared__ __align__(16) unsigned short Bs[64][40];
  int tid = threadIdx.x;
  int l = tid & 63, w = tid >> 6;
  int bid = blockIdx.x;
  int rt = bid >> 4, ct = bid & 15;
  int row0 = rt*64, col0 = ct*64;

  f32x4 acc[4];
  #pragma unroll
  for (int cf=0; cf<4; ++cf) acc[cf] = 0.0f;

  int sr = tid >> 2, sc = (tid & 3)*8;
  const unsigned short* ga = gb + (size_t)(row0 + sr)*256 + sc;
  const unsigned short* gw = wb + (size_t)(col0 + sr)*256 + sc;

  for (int ks=0; ks<8; ++ks){
    us8 av = *(const us8*)(ga + ks*32);
    us8 bv = *(const us8*)(gw + ks*32);
    *(us8*)&As[sr][sc] = av;
    *(us8*)&Bs[sr][sc] = bv;
    __syncthreads();
    bf16x8 af = *(const bf16x8*)&As[w*16 + (l&15)][(l>>4)*8];
    #pragma unroll
    for (int cf=0; cf<4; ++cf){
      bf16x8 bf = *(const bf16x8*)&Bs[cf*16 + (l&15)][(l>>4)*8];
      acc[cf] = __builtin_amdgcn_mfma_f32_16x16x32_bf16(af, bf, acc[cf], 0,0,0);
    }
    __syncthreads();
  }

  // epilogue: C frag col=lane&15 (+16*cf), row=(lane>>4)*4+i  [m89-verified]
  int h = (col0 >> 6) & 7;
  unsigned short* outp = (col0 < 512) ? qb : kb;
  #pragma unroll
  for (int cf=0; cf<4; ++cf){
    int z = cf*16 + (l & 15);
    #pragma unroll
    for (int i=0; i<4; ++i){
      int row = row0 + w*16 + (l>>4)*4 + i;
      int b_ = row >> 11, n_ = row & 2047;
      outp[(size_t)((b_*8 + h)*2048 + n_)*64 + z] = f2bf(acc[cf][i]);
    }
  }
}

// ---------------------------------------------------------------------------
// Kernel 2: fused scores + head-mix + exp accumulation (flash-LSE, no max
// tracking: |logits| ~ 1e-5 so exp never overflows).
// One wave per block. Grid = (b, m-chunk, n-tile): bid = ((b*8+ms)*128+nt)
// so consecutive blocks share the same K m-chunk (L2 locality).
// Each wave: 16 q-rows, all 8 heads (S tiles in AGPRs), accumulates
// sum_m exp(L[n,m,g]) per (row, g) over its 256-wide m-chunk.
// ---------------------------------------------------------------------------
__global__ __launch_bounds__(64) void attn_kernel(
    const unsigned short* __restrict__ qb, const unsigned short* __restrict__ kb,
    const float* __restrict__ Hw, const float* __restrict__ betas,
    const int* __restrict__ ds, float* __restrict__ partial)
{
  int l = threadIdx.x;
  int bid = blockIdx.x;
  int nt = bid & 127, ms = (bid >> 7) & 7, b = bid >> 10;
  int nb = ds[b];
  int n0 = nt*16;
  if (n0 >= nb) return;   // whole row-tile masked; finalize never reads it

  // w2[h][g] = betas[h]*Hw[h][g], forced to SGPRs (uniform)
  float w2[8][8];
  #pragma unroll
  for (int h=0; h<8; ++h){
    float bh = betas[h];
    #pragma unroll
    for (int gg=0; gg<8; ++gg){
      float v = bh * Hw[h*8 + gg];
      w2[h][gg] = __uint_as_float(__builtin_amdgcn_readfirstlane(__float_as_uint(v)));
    }
  }

  int lr = l & 15, lk = (l >> 4)*8;
  // Q fragments: A-frag row = lane&15, k = (lane>>4)*8 + i (contiguous 16B)
  bf16x8 qf[8][2];
  #pragma unroll
  for (int h=0; h<8; ++h){
    const unsigned short* qp = qb + (size_t)((b*8 + h)*2048 + n0 + lr)*64 + lk;
    qf[h][0] = *(const bf16x8*)qp;
    qf[h][1] = *(const bf16x8*)(qp + 32);
  }

  float acc[8][4];
  #pragma unroll
  for (int gg=0; gg<8; ++gg)
    #pragma unroll
    for (int i=0; i<4; ++i) acc[gg][i] = 0.0f;

  int mstart = ms*CHUNK;
  int mend = mstart + CHUNK; if (mend > nb) mend = nb;

  for (int m0 = mstart; m0 < mend; m0 += 16){
    // prefetch all 16 K fragments (B-frag col = lane&15 -> key row m0+col)
    bf16x8 kv[8][2];
    #pragma unroll
    for (int h=0; h<8; ++h){
      const unsigned short* kp = kb + (size_t)((b*8 + h)*2048 + m0 + lr)*64 + lk;
      kv[h][0] = *(const bf16x8*)kp;
      kv[h][1] = *(const bf16x8*)(kp + 32);
    }
    f32x4 s[8];
    #pragma unroll
    for (int h=0; h<8; ++h){
      f32x4 t = 0.0f;
      t = __builtin_amdgcn_mfma_f32_16x16x32_bf16(qf[h][0], kv[h][0], t, 0,0,0);
      t = __builtin_amdgcn_mfma_f32_16x16x32_bf16(qf[h][1], kv[h][1], t, 0,0,0);
      s[h] = t;
    }
    // column validity (m-tail mask); C-frag col = lane&15 for all i
    float sel = ((m0 + lr) < nb) ? 1.0f : 0.0f;
    #pragma unroll
    for (int gg=0; gg<8; ++gg){
      #pragma unroll
      for (int i=0; i<4; ++i){
        float L = 0.0f;
        #pragma unroll
        for (int h=0; h<8; ++h) L = fmaf(w2[h][gg], s[h][i], L);
        acc[gg][i] += sel * __expf(L);
      }
    }
  }

  // reduce over the 16 lanes sharing a row (xor masks 1,2,4,8 stay in-group)
  #pragma unroll
  for (int gg=0; gg<8; ++gg){
    #pragma unroll
    for (int i=0; i<4; ++i){
      float v = acc[gg][i];
      v += __shfl_xor(v, 1);
      v += __shfl_xor(v, 2);
      v += __shfl_xor(v, 4);
      v += __shfl_xor(v, 8);
      acc[gg][i] = v;
    }
  }
  // lane (l&15)==g writes g's partial; static indices only (no scratch)
  #pragma unroll
  for (int gg=0; gg<8; ++gg){
    if (lr == gg){
      #pragma unroll
      for (int i=0; i<4; ++i){
        int n = n0 + (l>>4)*4 + i;
        partial[(size_t)((b*2048 + n)*8 + gg)*8 + ms] = acc[gg][i];
      }
    }
  }
}

// ---------------------------------------------------------------------------
// Kernel 3: finalize. lse = log(sum of 8 split partials); skip rows >= nb;
// energy -= lse / beta_g. 64 blocks, per-wave reduce, one atomicAdd per wave.
// ---------------------------------------------------------------------------
__global__ __launch_bounds__(256) void fin_kernel(
    const float* __restrict__ partial, const float* __restrict__ betas,
    const int* __restrict__ ds, float* __restrict__ out)
{
  int tid = blockIdx.x*256 + threadIdx.x;       // 0..16383
  int g = tid & 7;                               // preserved under +=16384
  float ibg = 1.0f / betas[g];
  float local = 0.0f;
  for (int idx = tid; idx < BB*NN*8; idx += 16384){
    int n = (idx >> 3) & 2047, b = idx >> 14;
    if (n < ds[b]){
      const float* p = partial + (size_t)idx*8;
      float ssum = 0.0f;
      #pragma unroll
      for (int s=0; s<8; ++s) ssum += p[s];
      local += __logf(ssum) * ibg;
    }
  }
  float v = local;
  #pragma unroll
  for (int m=1; m<64; m<<=1) v += __shfl_xor(v, m);
  if ((threadIdx.x & 63) == 0) atomicAdd(out, -v);
}

// ---------------------------------------------------------------------------
extern "C" void kernel_launch(void* const* d_in, const int* in_sizes, int n_in,
                              void* d_out, int out_size, void* d_ws, size_t ws_size,
                              hipStream_t stream)
{
  const float* g     = (const float*)d_in[0];
  const float* Wq    = (const float*)d_in[1];
  const float* Wk    = (const float*)d_in[2];
  const float* Hw    = (const float*)d_in[3];
  const float* betas = (const float*)d_in[4];
  const int*   ds    = (const int*)d_in[5];
  float* out = (float*)d_out;

  char* base = (char*)d_ws;
  unsigned short* gb      = (unsigned short*)(base);             //  4,194,304 B
  unsigned short* wb      = (unsigned short*)(base +  4194304);  //    524,288 B
  unsigned short* qb      = (unsigned short*)(base +  4718592);  //  8,388,608 B
  unsigned short* kb      = (unsigned short*)(base + 13107200);  //  8,388,608 B
  float*          partial = (float*)         (base + 21495808);  //  2,097,152 B
  // total 23,592,960 B of d_ws

  cvt_kernel <<<dim3(2304), dim3(256), 0, stream>>>(g, Wq, Wk, gb, wb, out);
  proj_kernel<<<dim3(2048), dim3(256), 0, stream>>>(gb, wb, qb, kb);
  attn_kernel<<<dim3(4096), dim3(64),  0, stream>>>(qb, kb, Hw, betas, ds, partial);
  fin_kernel <<<dim3(64),   dim3(256), 0, stream>>>(partial, betas, ds, out);
}